// Round 3
// baseline (242.653 us; speedup 1.0000x reference)
//
#include <hip/hip_runtime.h>

namespace {

constexpr float FF[12] = {0.0144f, 0.0272f, 0.0526f, 0.0972f, 0.193f, 0.63f,
                          -0.63f, -0.193f, -0.0972f, -0.0526f, -0.0272f, -0.0144f};
constexpr float SQ2   = 1.41421356237309515f;
constexpr float NISQ2 = -0.70710678118654752f;

__device__ __forceinline__ void fma4(float4& o, float s, const float4& v) {
  o.x += s * v.x; o.y += s * v.y; o.z += s * v.z; o.w += s * v.w;
}

// hconv of one 20-float window -> one float4 (4 output cols).
// SH = 8 - O: 3 for offset-5, 2 for offset-6.
template <int SH>
__device__ __forceinline__ float4 hrow_conv(const float* w) {
  float4 o = make_float4(0.f, 0.f, 0.f, 0.f);
#pragma unroll
  for (int a = 0; a < 12; ++a) {
    const float fa = FF[a];
    o.x += fa * w[SH + 0 + a];
    o.y += fa * w[SH + 1 + a];
    o.z += fa * w[SH + 2 + a];
    o.w += fa * w[SH + 3 + a];
  }
  return o;
}

}  // namespace

// ---------------- Stage 1: fbrec(Y0, Y1, '2c', 'per') -> x (8,64,128,256) ----------------
// 512 threads, LDS 66 KB -> 2 blocks/CU. One block per plane, 512 planes.
// Thread task: 8-row x 1-group tile (16 strips x 32 groups = 512 tasks).
__global__ __launch_bounds__(512, 4) void s1_kernel(
    const float* __restrict__ y0, const float* __restrict__ y1,
    const float* __restrict__ y2, const float* __restrict__ y3,
    float* __restrict__ xout) {
  __shared__ float bufF[128 * 132];
  float4* buf4 = reinterpret_cast<float4*>(bufF);
  constexpr int SG = 33;  // row stride in float4 groups (32 + 1 pad)

  const int p  = blockIdx.x;
  const int b  = p >> 6;
  const int cc = p & 63;
  const int sub = (b * 32 + (cc & 31)) << 14;
  const float4* Y04 = reinterpret_cast<const float4*>((cc < 32 ? y1 : y2) + sub);
  const float4* Y14 = reinterpret_cast<const float4*>((cc < 32 ? y0 : y3) + sub);
  float4* xp4 = reinterpret_cast<float4*>(xout + (size_t)p * 32768);

  const int tid = threadIdx.x;
  const int j  = tid & 31;         // group 0..31
  const int i0 = (tid >> 5) * 8;   // strip base row

  // ---- Phase 1: p1 = NISQ2 * (Y1 + hconv5(vconv5(Y0))), source = GLOBAL Y0 ----
  float4 acc[8];
#pragma unroll
  for (int k = 0; k < 8; ++k) acc[k] = make_float4(0.f, 0.f, 0.f, 0.f);
#pragma unroll
  for (int d = 0; d < 19; ++d) {
    const int r = (i0 + d - 5) & 127;
    float w[20];
#pragma unroll
    for (int dg = 0; dg < 5; ++dg) {
      float4 v = Y04[r * 32 + ((j + dg - 2) & 31)];
      w[4 * dg + 0] = v.x; w[4 * dg + 1] = v.y; w[4 * dg + 2] = v.z; w[4 * dg + 3] = v.w;
    }
    const float4 h = hrow_conv<3>(w);
#pragma unroll
    for (int k = 0; k < 8; ++k) {
      const int a = d - k;
      if (a >= 0 && a < 12) fma4(acc[k], FF[a], h);
    }
  }
#pragma unroll
  for (int k = 0; k < 8; ++k) {
    float4 yv = Y14[(i0 + k) * 32 + j];
    float4 pv;
    pv.x = NISQ2 * (yv.x + acc[k].x);
    pv.y = NISQ2 * (yv.y + acc[k].y);
    pv.z = NISQ2 * (yv.z + acc[k].z);
    pv.w = NISQ2 * (yv.w + acc[k].w);
    buf4[(i0 + k) * SG + j] = pv;
  }
  __syncthreads();  // b1: p1 visible

  // ---- Phase 2: odd-J gather -> regs; p0 = SQ2*Y0 + hconv6(vconv6(p1)), p1 from LDS ----
  float xodd[32];
#pragma unroll
  for (int k = 0; k < 16; ++k) {
    const int t = tid + k * 512;
    const int i2 = t >> 6, j4o = t & 63;
    const int m0 = 1 - (i2 & 1);
#pragma unroll
    for (int h = 0; h < 2; ++h) {
      const int jo = 4 * j4o + m0 + 2 * h;
      const int J = (i2 + jo) & 255;
      const int c = J >> 1;
      const int r = (i2 - 1 - c) & 127;
      xodd[2 * k + h] = bufF[r * 132 + c];
    }
  }
#pragma unroll
  for (int k = 0; k < 8; ++k) acc[k] = make_float4(0.f, 0.f, 0.f, 0.f);
#pragma unroll
  for (int d = 0; d < 19; ++d) {
    const int r = (i0 + d - 6) & 127;
    float w[20];
#pragma unroll
    for (int dg = 0; dg < 5; ++dg) {
      float4 v = buf4[r * SG + ((j + dg - 2) & 31)];
      w[4 * dg + 0] = v.x; w[4 * dg + 1] = v.y; w[4 * dg + 2] = v.z; w[4 * dg + 3] = v.w;
    }
    const float4 h = hrow_conv<2>(w);
#pragma unroll
    for (int k = 0; k < 8; ++k) {
      const int a = d - k;
      if (a >= 0 && a < 12) fma4(acc[k], FF[a], h);
    }
  }
  float4 pv[8];
#pragma unroll
  for (int k = 0; k < 8; ++k) {
    float4 yv = Y04[(i0 + k) * 32 + j];
    pv[k].x = SQ2 * yv.x + acc[k].x;
    pv[k].y = SQ2 * yv.y + acc[k].y;
    pv[k].z = SQ2 * yv.z + acc[k].z;
    pv[k].w = SQ2 * yv.w + acc[k].w;
  }
  __syncthreads();  // b2: all p1 reads done
#pragma unroll
  for (int k = 0; k < 8; ++k) buf4[(i0 + k) * SG + j] = pv[k];
  __syncthreads();  // b3: p0 visible

  // ---- Phase 3: even-J gather, merge odd regs, coalesced write ----
#pragma unroll
  for (int k = 0; k < 16; ++k) {
    const int t = tid + k * 512;
    const int i2 = t >> 6, j4o = t & 63;
    float ev[2];
#pragma unroll
    for (int h = 0; h < 2; ++h) {
      const int me = (i2 & 1) + 2 * h;
      const int jo = 4 * j4o + me;
      const int J = (i2 + jo) & 255;
      const int c = J >> 1;
      const int r = (i2 - c) & 127;
      ev[h] = bufF[r * 132 + c];
    }
    const float o0 = xodd[2 * k + 0], o1 = xodd[2 * k + 1];
    const bool sw = (i2 & 1) != 0;
    xp4[t] = make_float4(sw ? o0 : ev[0], sw ? ev[0] : o0,
                         sw ? o1 : ev[1], sw ? ev[1] : o1);
  }
}

// ---------------- Stage 2: fbrec(x0, x1, '1r', 'qper_col') -> out (8,32,256,256) -----------
// 1024 threads, LDS 130 KB -> 1 block/CU. One block per output plane, 256 planes.
// Thread task: 8-row x 1-group tile (16 strips x 64 groups = 1024 tasks).
__global__ __launch_bounds__(1024, 4) void s2_kernel(const float* __restrict__ x,
                                                     float* __restrict__ out) {
  __shared__ float bufF[128 * 260];
  float4* buf4 = reinterpret_cast<float4*>(bufF);
  constexpr int SG = 65;  // row stride in float4 groups (64 + 1 pad)

  const int q = blockIdx.x;
  const int b = q >> 5, c = q & 31;
  const float4* x04 = reinterpret_cast<const float4*>(x + (size_t)(b * 64 + c) * 32768);
  const float4* x14 = reinterpret_cast<const float4*>(x + (size_t)(b * 64 + 32 + c) * 32768);
  float4* op4 = reinterpret_cast<float4*>(out + (size_t)q * 65536);

  const int tid = threadIdx.x;
  const int j  = tid & 63;
  const int i0 = (tid >> 6) * 8;

  // ---- Phase 1: p1 = NISQ2 * (x1 + hconv5(vconv5(x0^qper))), source = GLOBAL x0 ----
  float4 acc[8];
#pragma unroll
  for (int k = 0; k < 8; ++k) acc[k] = make_float4(0.f, 0.f, 0.f, 0.f);
#pragma unroll
  for (int d = 0; d < 19; ++d) {
    const int rr = i0 + d - 5;
    const int r = rr & 127;
    const int gx = ((unsigned)rr < 128u) ? 0 : 32;  // qper_col: wrapped row -> col+128
    float w[20];
#pragma unroll
    for (int dg = 0; dg < 5; ++dg) {
      float4 v = x04[r * 64 + (((j + dg - 2) & 63) ^ gx)];
      w[4 * dg + 0] = v.x; w[4 * dg + 1] = v.y; w[4 * dg + 2] = v.z; w[4 * dg + 3] = v.w;
    }
    const float4 h = hrow_conv<3>(w);
#pragma unroll
    for (int k = 0; k < 8; ++k) {
      const int a = d - k;
      if (a >= 0 && a < 12) fma4(acc[k], FF[a], h);
    }
  }
#pragma unroll
  for (int k = 0; k < 8; ++k) {
    float4 xv = x14[(i0 + k) * 64 + j];
    float4 pv;
    pv.x = NISQ2 * (xv.x + acc[k].x);
    pv.y = NISQ2 * (xv.y + acc[k].y);
    pv.z = NISQ2 * (xv.z + acc[k].z);
    pv.w = NISQ2 * (xv.w + acc[k].w);
    buf4[(i0 + k) * SG + j] = pv;
  }
  __syncthreads();  // b1: p1 visible

  // ---- Phase 2: odd-I gather -> regs; p0 = SQ2*x0 + hconv6(vconv6(p1^qper)), p1 from LDS ----
  float oodd[32];
#pragma unroll
  for (int k = 0; k < 16; ++k) {
    const int t = tid + k * 1024;
    const int i2 = t >> 6, j4o = t & 63;
    const int m0 = 1 - (i2 & 1);
#pragma unroll
    for (int h = 0; h < 2; ++h) {
      const int jo = 4 * j4o + m0 + 2 * h;
      const int I = (i2 + jo) & 255;
      const int r2 = I >> 1;
      const int c2 = (jo - 1 - r2) & 255;
      oodd[2 * k + h] = bufF[r2 * 260 + c2];
    }
  }
#pragma unroll
  for (int k = 0; k < 8; ++k) acc[k] = make_float4(0.f, 0.f, 0.f, 0.f);
#pragma unroll
  for (int d = 0; d < 19; ++d) {
    const int rr = i0 + d - 6;
    const int r = rr & 127;
    const int gx = ((unsigned)rr < 128u) ? 0 : 32;
    float w[20];
#pragma unroll
    for (int dg = 0; dg < 5; ++dg) {
      float4 v = buf4[r * SG + (((j + dg - 2) & 63) ^ gx)];
      w[4 * dg + 0] = v.x; w[4 * dg + 1] = v.y; w[4 * dg + 2] = v.z; w[4 * dg + 3] = v.w;
    }
    const float4 h = hrow_conv<2>(w);
#pragma unroll
    for (int k = 0; k < 8; ++k) {
      const int a = d - k;
      if (a >= 0 && a < 12) fma4(acc[k], FF[a], h);
    }
  }
  float4 pv[8];
#pragma unroll
  for (int k = 0; k < 8; ++k) {
    float4 xv = x04[(i0 + k) * 64 + j];
    pv[k].x = SQ2 * xv.x + acc[k].x;
    pv[k].y = SQ2 * xv.y + acc[k].y;
    pv[k].z = SQ2 * xv.z + acc[k].z;
    pv[k].w = SQ2 * xv.w + acc[k].w;
  }
  __syncthreads();  // b2: all p1 reads done
#pragma unroll
  for (int k = 0; k < 8; ++k) buf4[(i0 + k) * SG + j] = pv[k];
  __syncthreads();  // b3: p0 visible

  // ---- Phase 3: even-I gather, merge odd regs, coalesced write ----
#pragma unroll
  for (int k = 0; k < 16; ++k) {
    const int t = tid + k * 1024;
    const int i2 = t >> 6, j4o = t & 63;
    float ev[2];
#pragma unroll
    for (int h = 0; h < 2; ++h) {
      const int me = (i2 & 1) + 2 * h;
      const int jo = 4 * j4o + me;
      const int I = (i2 + jo) & 255;
      const int r2 = I >> 1;
      const int c2 = (jo - r2) & 255;
      ev[h] = bufF[r2 * 260 + c2];
    }
    const float o0 = oodd[2 * k + 0], o1 = oodd[2 * k + 1];
    const bool sw = (i2 & 1) != 0;
    op4[t] = make_float4(sw ? o0 : ev[0], sw ? ev[0] : o0,
                         sw ? o1 : ev[1], sw ? ev[1] : o1);
  }
}

extern "C" void kernel_launch(void* const* d_in, const int* in_sizes, int n_in,
                              void* d_out, int out_size, void* d_ws, size_t ws_size,
                              hipStream_t stream) {
  const float* y0 = (const float*)d_in[0];
  const float* y1 = (const float*)d_in[1];
  const float* y2 = (const float*)d_in[2];
  const float* y3 = (const float*)d_in[3];
  float* xws = (float*)d_ws;           // (8,64,128,256) fp32 = 64 MiB intermediate
  float* outp = (float*)d_out;         // (8,32,256,256) fp32

  s1_kernel<<<512, 512, 0, stream>>>(y0, y1, y2, y3, xws);
  s2_kernel<<<256, 1024, 0, stream>>>(xws, outp);
}